// Round 1
// baseline (414.483 us; speedup 1.0000x reference)
//
#include <hip/hip_runtime.h>

#define B_   64
#define S_   1024
#define F_   768
#define H_   12
#define DH_  64
#define P2_  64
#define NQKV 2304   // 3*768

using bf16x8 = __attribute__((ext_vector_type(8))) short;
using f32x4  = __attribute__((ext_vector_type(4))) float;

__device__ __forceinline__ unsigned short f2bf(float f) {
    union { float f; unsigned u; } v;
    v.f = f;
    unsigned r = v.u + 0x7FFF + ((v.u >> 16) & 1);   // RNE
    return (unsigned short)(r >> 16);
}

// ---------------------------------------------------------------------------
// Kernel 1: copy tail x[:,64:,:] -> out[:,64:,:]  AND cast window to bf16 ws
// ---------------------------------------------------------------------------
__global__ __launch_bounds__(256) void copy_cast_kernel(
        const float* __restrict__ x, float* __restrict__ out,
        unsigned short* __restrict__ xw) {
    const int total4  = B_ * S_ * F_ / 4;      // 12,582,912
    const int batch4  = S_ * F_ / 4;           // 196,608
    const int window4 = P2_ * F_ / 4;          // 12,288
    int stride = gridDim.x * blockDim.x;
    for (int i = blockIdx.x * blockDim.x + threadIdx.x; i < total4; i += stride) {
        float4 v = reinterpret_cast<const float4*>(x)[i];
        int r = i % batch4;
        if (r >= window4) {
            reinterpret_cast<float4*>(out)[i] = v;
        } else {
            int b = i / batch4;
            ushort4 h;
            h.x = f2bf(v.x); h.y = f2bf(v.y); h.z = f2bf(v.z); h.w = f2bf(v.w);
            reinterpret_cast<ushort4*>(xw)[b * window4 + r] = h;
        }
    }
}

// ---------------------------------------------------------------------------
// Kernel 2: cast Wq|Wk|Wv -> Wqkv bf16 (2304x768), Wo -> bf16, bias concat f32
// ---------------------------------------------------------------------------
__global__ __launch_bounds__(256) void wcast_kernel(
        const float* __restrict__ Wq, const float* __restrict__ Wk,
        const float* __restrict__ Wv, const float* __restrict__ Wo,
        const float* __restrict__ bq, const float* __restrict__ bk,
        const float* __restrict__ bv,
        unsigned short* __restrict__ Wqkv, unsigned short* __restrict__ Wob,
        float* __restrict__ biasq) {
    const int W4     = 589824 / 4;             // 147,456
    const int total4 = 4 * W4 + 576;
    int stride = gridDim.x * blockDim.x;
    for (int i4 = blockIdx.x * blockDim.x + threadIdx.x; i4 < total4; i4 += stride) {
        if (i4 < 3 * W4) {
            int which = i4 / W4, local = i4 % W4;
            const float* src = (which == 0) ? Wq : (which == 1) ? Wk : Wv;
            float4 v = reinterpret_cast<const float4*>(src)[local];
            ushort4 h;
            h.x = f2bf(v.x); h.y = f2bf(v.y); h.z = f2bf(v.z); h.w = f2bf(v.w);
            reinterpret_cast<ushort4*>(Wqkv)[i4] = h;
        } else if (i4 < 4 * W4) {
            int local = i4 - 3 * W4;
            float4 v = reinterpret_cast<const float4*>(Wo)[local];
            ushort4 h;
            h.x = f2bf(v.x); h.y = f2bf(v.y); h.z = f2bf(v.z); h.w = f2bf(v.w);
            reinterpret_cast<ushort4*>(Wob)[local] = h;
        } else {
            int j4 = i4 - 4 * W4;              // 0..575
            int seg = j4 / 192, local = j4 % 192;
            const float* src = (seg == 0) ? bq : (seg == 1) ? bk : bv;
            reinterpret_cast<float4*>(biasq)[j4] =
                reinterpret_cast<const float4*>(src)[local];
        }
    }
}

// ---------------------------------------------------------------------------
// GEMM: C[M,N] = A[M,768] * B[N,768]^T + bias[N]
//   A, B bf16 row-major (K contiguous). 128x128 tile, BK=64, 4 waves.
//   LDS XOR-swizzled (chunk ^= row&7) so ds_read_b128 is conflict-free.
//   OUT_MODE 0: write bf16 to Y[m*2304+n]
//   OUT_MODE 1: write f32 to out[(m>>6)*786432 + (m&63)*768 + n]
// ---------------------------------------------------------------------------
template <int OUT_MODE>
__global__ __launch_bounds__(256) void gemm_kernel(
        const unsigned short* __restrict__ A, const unsigned short* __restrict__ Bw,
        const float* __restrict__ bias, void* __restrict__ Cout) {
    __shared__ __align__(16) unsigned char lds[32768];
    unsigned char* As = lds;
    unsigned char* Bs = lds + 16384;
    const int tid  = threadIdx.x;
    const int lane = tid & 63;
    const int w    = tid >> 6;
    const int wr   = w >> 1, wc = w & 1;
    const int m0 = blockIdx.y * 128, n0 = blockIdx.x * 128;
    const int ldc = gridDim.x << 7;            // 2304 or 768

    f32x4 acc[4][4] = {};

    for (int kt = 0; kt < 768; kt += 64) {
        __syncthreads();
#pragma unroll
        for (int p = 0; p < 4; ++p) {
            int id  = p * 256 + tid;           // 0..1023
            int row = id >> 3, c = id & 7;
            int4 va = *reinterpret_cast<const int4*>(A  + (m0 + row) * 768 + kt + c * 8);
            *reinterpret_cast<int4*>(As + row * 128 + ((c ^ (row & 7)) << 4)) = va;
            int4 vb = *reinterpret_cast<const int4*>(Bw + (n0 + row) * 768 + kt + c * 8);
            *reinterpret_cast<int4*>(Bs + row * 128 + ((c ^ (row & 7)) << 4)) = vb;
        }
        __syncthreads();
#pragma unroll
        for (int kk = 0; kk < 2; ++kk) {
            const int g = kk * 4 + (lane >> 4);
            bf16x8 a[4], b[4];
#pragma unroll
            for (int i = 0; i < 4; ++i) {
                int row = wr * 64 + i * 16 + (lane & 15);
                a[i] = *reinterpret_cast<const bf16x8*>(As + row * 128 + ((g ^ (row & 7)) << 4));
            }
#pragma unroll
            for (int j = 0; j < 4; ++j) {
                int row = wc * 64 + j * 16 + (lane & 15);
                b[j] = *reinterpret_cast<const bf16x8*>(Bs + row * 128 + ((g ^ (row & 7)) << 4));
            }
#pragma unroll
            for (int i = 0; i < 4; ++i)
#pragma unroll
                for (int j = 0; j < 4; ++j)
                    acc[i][j] = __builtin_amdgcn_mfma_f32_16x16x32_bf16(a[i], b[j], acc[i][j], 0, 0, 0);
        }
    }

    float bj[4];
#pragma unroll
    for (int j = 0; j < 4; ++j) bj[j] = bias[n0 + wc * 64 + j * 16 + (lane & 15)];

#pragma unroll
    for (int i = 0; i < 4; ++i) {
        int mrow = m0 + wr * 64 + i * 16 + ((lane >> 4) << 2);
#pragma unroll
        for (int j = 0; j < 4; ++j) {
            int n = n0 + wc * 64 + j * 16 + (lane & 15);
#pragma unroll
            for (int r = 0; r < 4; ++r) {
                float v = acc[i][j][r] + bj[j];
                if constexpr (OUT_MODE == 0) {
                    reinterpret_cast<unsigned short*>(Cout)[(mrow + r) * 2304 + n] = f2bf(v);
                } else {
                    int m = mrow + r;
                    reinterpret_cast<float*>(Cout)[(m >> 6) * 786432 + (m & 63) * 768 + n] = v;
                }
            }
        }
    }
}

// ---------------------------------------------------------------------------
// Attention: one block per (b,h). Q,K row-major in LDS; V transposed.
// scores = QK^T/8, softmax (in-register over 16-lane groups), O = P V.
// ---------------------------------------------------------------------------
__global__ __launch_bounds__(256) void attn_kernel(
        const unsigned short* __restrict__ Y, unsigned short* __restrict__ O) {
    const int bh = blockIdx.x;
    const int b = bh / 12, h = bh % 12;
    __shared__ __align__(16) unsigned char lds[32768];
    unsigned char* Qs = lds;
    unsigned char* Ks = lds + 8192;
    unsigned char* Vt = lds + 16384;
    unsigned char* Ps = lds + 24576;
    const int tid = threadIdx.x, lane = tid & 63, w = tid >> 6;

    // stage Q, K (row-major swizzled), V transposed (Vt[d][t])
    for (int c = tid; c < 512; c += 256) {
        int row = c >> 3, cc = c & 7;
        const unsigned short* src = Y + (size_t)(b * 64 + row) * NQKV + h * 64 + cc * 8;
        *reinterpret_cast<int4*>(Qs + row * 128 + ((cc ^ (row & 7)) << 4)) =
            *reinterpret_cast<const int4*>(src);
        *reinterpret_cast<int4*>(Ks + row * 128 + ((cc ^ (row & 7)) << 4)) =
            *reinterpret_cast<const int4*>(src + 768);
        int4 vv = *reinterpret_cast<const int4*>(src + 1536);
        const unsigned short* vs = reinterpret_cast<const unsigned short*>(&vv);
#pragma unroll
        for (int u = 0; u < 8; ++u) {
            int d = cc * 8 + u;
            *reinterpret_cast<unsigned short*>(
                Vt + d * 128 + (((row >> 3) ^ u) << 4) + ((row & 7) << 1)) = vs[u];
        }
    }
    __syncthreads();

    // QK^T : wave w computes rows [w*16, w*16+16) x all 64 cols
    f32x4 accS[4] = {};
#pragma unroll
    for (int kk = 0; kk < 2; ++kk) {
        const int g = kk * 4 + (lane >> 4);
        int qrow = w * 16 + (lane & 15);
        bf16x8 a = *reinterpret_cast<const bf16x8*>(Qs + qrow * 128 + ((g ^ (qrow & 7)) << 4));
#pragma unroll
        for (int j = 0; j < 4; ++j) {
            int krow = j * 16 + (lane & 15);
            bf16x8 bb = *reinterpret_cast<const bf16x8*>(Ks + krow * 128 + ((g ^ (krow & 7)) << 4));
            accS[j] = __builtin_amdgcn_mfma_f32_16x16x32_bf16(a, bb, accS[j], 0, 0, 0);
        }
    }

    // softmax per row; rows owned by 16-lane groups (same lane>>4)
#pragma unroll
    for (int r = 0; r < 4; ++r) {
        float v0 = accS[0][r], v1 = accS[1][r], v2 = accS[2][r], v3 = accS[3][r];
        float mx = fmaxf(fmaxf(v0, v1), fmaxf(v2, v3));
        mx = fmaxf(mx, __shfl_xor(mx, 1));
        mx = fmaxf(mx, __shfl_xor(mx, 2));
        mx = fmaxf(mx, __shfl_xor(mx, 4));
        mx = fmaxf(mx, __shfl_xor(mx, 8));
        float p0 = __expf((v0 - mx) * 0.125f);
        float p1 = __expf((v1 - mx) * 0.125f);
        float p2 = __expf((v2 - mx) * 0.125f);
        float p3 = __expf((v3 - mx) * 0.125f);
        float sm = p0 + p1 + p2 + p3;
        sm += __shfl_xor(sm, 1);
        sm += __shfl_xor(sm, 2);
        sm += __shfl_xor(sm, 4);
        sm += __shfl_xor(sm, 8);
        float inv = 1.0f / sm;
        int srow = w * 16 + ((lane >> 4) << 2) + r;
        float pv[4] = {p0 * inv, p1 * inv, p2 * inv, p3 * inv};
#pragma unroll
        for (int j = 0; j < 4; ++j) {
            int t = j * 16 + (lane & 15);
            *reinterpret_cast<unsigned short*>(
                Ps + srow * 128 + (((t >> 3) ^ (srow & 7)) << 4) + ((t & 7) << 1)) = f2bf(pv[j]);
        }
    }
    __syncthreads();

    // O = P V  (A = P from Ps, B = V via Vt[d][t] rows contiguous in t)
    f32x4 accO[4] = {};
#pragma unroll
    for (int kk = 0; kk < 2; ++kk) {
        const int g = kk * 4 + (lane >> 4);
        int prow = w * 16 + (lane & 15);
        bf16x8 a = *reinterpret_cast<const bf16x8*>(Ps + prow * 128 + ((g ^ (prow & 7)) << 4));
#pragma unroll
        for (int j = 0; j < 4; ++j) {
            int drow = j * 16 + (lane & 15);
            bf16x8 bb = *reinterpret_cast<const bf16x8*>(Vt + drow * 128 + ((g ^ (drow & 7)) << 4));
            accO[j] = __builtin_amdgcn_mfma_f32_16x16x32_bf16(a, bb, accO[j], 0, 0, 0);
        }
    }

#pragma unroll
    for (int j = 0; j < 4; ++j) {
        int d = h * 64 + j * 16 + (lane & 15);
#pragma unroll
        for (int r = 0; r < 4; ++r) {
            int s = w * 16 + ((lane >> 4) << 2) + r;
            O[(size_t)(b * 64 + s) * 768 + d] = f2bf(accO[j][r]);
        }
    }
}

// ---------------------------------------------------------------------------
extern "C" void kernel_launch(void* const* d_in, const int* in_sizes, int n_in,
                              void* d_out, int out_size, void* d_ws, size_t ws_size,
                              hipStream_t stream) {
    const float* x  = (const float*)d_in[0];
    const float* Wq = (const float*)d_in[1];
    const float* bq = (const float*)d_in[2];
    const float* Wk = (const float*)d_in[3];
    const float* bk = (const float*)d_in[4];
    const float* Wv = (const float*)d_in[5];
    const float* bv = (const float*)d_in[6];
    const float* Wo = (const float*)d_in[7];
    const float* bo = (const float*)d_in[8];
    float* out = (float*)d_out;
    char* ws = (char*)d_ws;

    unsigned short* xw   = (unsigned short*)(ws);              //  6,291,456 B
    unsigned short* Wqkv = (unsigned short*)(ws + 6291456);    //  3,538,944 B
    unsigned short* Wob  = (unsigned short*)(ws + 9830400);    //  1,179,648 B
    float*          bqv  = (float*)(ws + 11010048);            //      9,216 B
    unsigned short* Y    = (unsigned short*)(ws + 11019264);   // 18,874,368 B
    unsigned short* Obuf = (unsigned short*)(ws + 29893632);   //  6,291,456 B

    copy_cast_kernel<<<2048, 256, 0, stream>>>(x, out, xw);
    wcast_kernel<<<1024, 256, 0, stream>>>(Wq, Wk, Wv, Wo, bq, bk, bv, Wqkv, Wob, bqv);
    gemm_kernel<0><<<dim3(18, 32), 256, 0, stream>>>(xw, Wqkv, bqv, (void*)Y);
    attn_kernel<<<768, 256, 0, stream>>>(Y, Obuf);
    gemm_kernel<1><<<dim3(6, 32), 256, 0, stream>>>(Obuf, Wob, bo, (void*)out);
}

// Round 2
// 413.995 us; speedup vs baseline: 1.0012x; 1.0012x over previous
//
#include <hip/hip_runtime.h>

#define B_   64
#define S_   1024
#define F_   768
#define H_   12
#define DH_  64
#define P2_  64
#define NQKV 2304   // 3*768

using bf16x8 = __attribute__((ext_vector_type(8))) short;
using f32x4  = __attribute__((ext_vector_type(4))) float;

__device__ __forceinline__ unsigned short f2bf(float f) {
    union { float f; unsigned u; } v;
    v.f = f;
    unsigned r = v.u + 0x7FFF + ((v.u >> 16) & 1);   // RNE
    return (unsigned short)(r >> 16);
}

// async global->LDS, 16B per lane. LDS dst must be wave-uniform base;
// HW writes dst + lane*16. Global src is per-lane.
__device__ __forceinline__ void gll16(const unsigned short* g, unsigned char* l) {
    __builtin_amdgcn_global_load_lds(
        (const __attribute__((address_space(1))) unsigned int*)g,
        (__attribute__((address_space(3))) unsigned int*)l, 16, 0, 0);
}

// ---------------------------------------------------------------------------
// prep: cast x-window -> xw bf16, Wq|Wk|Wv -> Wqkv bf16, Wo -> Wob bf16,
//       concat bq|bk|bv -> bqv f32.   (~22 MB read, ~12 MB write)
// ---------------------------------------------------------------------------
__global__ __launch_bounds__(256) void prep_kernel(
        const float* __restrict__ x,
        const float* __restrict__ Wq, const float* __restrict__ Wk,
        const float* __restrict__ Wv, const float* __restrict__ Wo,
        const float* __restrict__ bq, const float* __restrict__ bk,
        const float* __restrict__ bv,
        unsigned short* __restrict__ xw, unsigned short* __restrict__ Wqkv,
        unsigned short* __restrict__ Wob, float* __restrict__ bqv) {
    const int NW = 786432;            // 64 * 64*768/4  (window float4s)
    const int W4 = 147456;            // 768*768/4
    int i = blockIdx.x * 256 + threadIdx.x;
    if (i < NW) {
        int b = i / 12288, r = i - b * 12288;          // 12288 = 64*768/4
        float4 v = reinterpret_cast<const float4*>(x)[b * 196608 + r];
        ushort4 h;
        h.x = f2bf(v.x); h.y = f2bf(v.y); h.z = f2bf(v.z); h.w = f2bf(v.w);
        reinterpret_cast<ushort4*>(xw)[i] = h;
    } else if (i < NW + 3 * W4) {
        int j = i - NW;
        int which = j / W4, local = j - which * W4;
        const float* src = (which == 0) ? Wq : (which == 1) ? Wk : Wv;
        float4 v = reinterpret_cast<const float4*>(src)[local];
        ushort4 h;
        h.x = f2bf(v.x); h.y = f2bf(v.y); h.z = f2bf(v.z); h.w = f2bf(v.w);
        reinterpret_cast<ushort4*>(Wqkv)[j] = h;
    } else if (i < NW + 4 * W4) {
        int local = i - NW - 3 * W4;
        float4 v = reinterpret_cast<const float4*>(Wo)[local];
        ushort4 h;
        h.x = f2bf(v.x); h.y = f2bf(v.y); h.z = f2bf(v.z); h.w = f2bf(v.w);
        reinterpret_cast<ushort4*>(Wob)[local] = h;
    } else if (i < NW + 4 * W4 + 576) {
        int j4 = i - NW - 4 * W4;                       // 0..575
        int seg = j4 / 192, local = j4 - seg * 192;
        const float* src = (seg == 0) ? bq : (seg == 1) ? bk : bv;
        reinterpret_cast<float4*>(bqv)[j4] =
            reinterpret_cast<const float4*>(src)[local];
    }
}

// ---------------------------------------------------------------------------
// GEMM body: C[M,N] = A[M,768] * B[N,768]^T + bias[N]
//   bf16 row-major operands. BK=64, 4 waves. global_load_lds 16B staging:
//   linear LDS dest, inverse-XOR-swizzled global source; XOR-swizzled read
//   (chunk ^= row&7) so ds_read_b128 is conflict-free.
// ---------------------------------------------------------------------------
template <int BM, int BN, int OUT_MODE>
__device__ __forceinline__ void gemm_body(
        int bx, int by,
        const unsigned short* __restrict__ A, const unsigned short* __restrict__ Bw,
        const float* __restrict__ bias, void* __restrict__ Cout) {
    constexpr int WC = (BN == 128) ? 2 : 1;
    constexpr int WR = 4 / WC;
    constexpr int MI = BM / WR / 16;
    constexpr int NJ = BN / WC / 16;
    constexpr int CA = BM / 32;       // gll16 calls/wave for A-tile
    constexpr int CB = BN / 32;
    __shared__ __align__(16) unsigned char lds[(BM + BN) * 128];
    unsigned char* As = lds;
    unsigned char* Bs = lds + BM * 128;
    const int tid  = threadIdx.x;
    const int lane = tid & 63;
    const int w    = tid >> 6;
    const int wr = w / WC, wc = w % WC;
    const int mbase = wr * (BM / WR), nbase = wc * (BN / WC);
    const int m0 = by * BM, n0 = bx * BN;
    const int lr = lane >> 3, lc = lane & 7;   // staging sub-coords

    f32x4 acc[MI][NJ] = {};

    for (int kt = 0; kt < 768; kt += 64) {
        __syncthreads();
#pragma unroll
        for (int p = 0; p < CA; ++p) {
            int row = (w * CA + p) * 8 + lr;
            gll16(A + (size_t)(m0 + row) * 768 + kt + ((lc ^ (row & 7)) << 3),
                  As + (w * CA + p) * 1024);
        }
#pragma unroll
        for (int p = 0; p < CB; ++p) {
            int row = (w * CB + p) * 8 + lr;
            gll16(Bw + (size_t)(n0 + row) * 768 + kt + ((lc ^ (row & 7)) << 3),
                  Bs + (w * CB + p) * 1024);
        }
        __syncthreads();
#pragma unroll
        for (int kk = 0; kk < 2; ++kk) {
            const int g = kk * 4 + (lane >> 4);
            bf16x8 a[MI], b[NJ];
#pragma unroll
            for (int i = 0; i < MI; ++i) {
                int row = mbase + i * 16 + (lane & 15);
                a[i] = *reinterpret_cast<const bf16x8*>(As + row * 128 + ((g ^ (row & 7)) << 4));
            }
#pragma unroll
            for (int j = 0; j < NJ; ++j) {
                int row = nbase + j * 16 + (lane & 15);
                b[j] = *reinterpret_cast<const bf16x8*>(Bs + row * 128 + ((g ^ (row & 7)) << 4));
            }
#pragma unroll
            for (int i = 0; i < MI; ++i)
#pragma unroll
                for (int j = 0; j < NJ; ++j)
                    acc[i][j] = __builtin_amdgcn_mfma_f32_16x16x32_bf16(a[i], b[j], acc[i][j], 0, 0, 0);
        }
    }

    float bj[NJ];
#pragma unroll
    for (int j = 0; j < NJ; ++j) bj[j] = bias[n0 + nbase + j * 16 + (lane & 15)];

#pragma unroll
    for (int i = 0; i < MI; ++i) {
        int mrow = m0 + mbase + i * 16 + ((lane >> 4) << 2);
#pragma unroll
        for (int j = 0; j < NJ; ++j) {
            int n = n0 + nbase + j * 16 + (lane & 15);
#pragma unroll
            for (int r = 0; r < 4; ++r) {
                float v = acc[i][j][r] + bj[j];
                if constexpr (OUT_MODE == 0) {
                    reinterpret_cast<unsigned short*>(Cout)[(size_t)(mrow + r) * 2304 + n] = f2bf(v);
                } else {
                    int m = mrow + r;
                    reinterpret_cast<float*>(Cout)[(size_t)(m >> 6) * 786432 + (m & 63) * 768 + n] = v;
                }
            }
        }
    }
}

// ---------------------------------------------------------------------------
// mega: blocks [0,2048) stream the tail copy (HBM-bound), blocks [2048,2624)
// run the QKV GEMM (MFMA-bound). Independent work -> overlaps on diff pipes.
// ---------------------------------------------------------------------------
__global__ __launch_bounds__(256) void mega_kernel(
        const float* __restrict__ x, float* __restrict__ out,
        const unsigned short* __restrict__ xw, const unsigned short* __restrict__ Wqkv,
        const float* __restrict__ bqv, unsigned short* __restrict__ Y) {
    if (blockIdx.x < 2048) {
        const int total4 = 11796480;            // 64 * 960*768/4
        int stride = 2048 * 256;
        for (int i = blockIdx.x * 256 + threadIdx.x; i < total4; i += stride) {
            int b = i / 184320, r = i - b * 184320;   // 184320 = 960*768/4
            int idx = b * 196608 + 12288 + r;
            reinterpret_cast<float4*>(out)[idx] =
                reinterpret_cast<const float4*>(x)[idx];
        }
    } else {
        int gid = blockIdx.x - 2048;
        gemm_body<128, 128, 0>(gid % 18, gid / 18, xw, Wqkv, bqv, (void*)Y);
    }
}

__global__ __launch_bounds__(256) void oproj_kernel(
        const unsigned short* __restrict__ Obuf, const unsigned short* __restrict__ Wob,
        const float* __restrict__ bo, float* __restrict__ out) {
    gemm_body<64, 64, 1>(blockIdx.x, blockIdx.y, Obuf, Wob, bo, (void*)out);
}

// ---------------------------------------------------------------------------
// Attention: one block per (b,h). Q,K row-major swizzled in LDS; V transposed.
// scores = QK^T/8, softmax in-register over 16-lane groups, O = P V.
// ---------------------------------------------------------------------------
__global__ __launch_bounds__(256) void attn_kernel(
        const unsigned short* __restrict__ Y, unsigned short* __restrict__ O) {
    const int bh = blockIdx.x;
    const int b = bh / 12, h = bh % 12;
    __shared__ __align__(16) unsigned char lds[32768];
    unsigned char* Qs = lds;
    unsigned char* Ks = lds + 8192;
    unsigned char* Vt = lds + 16384;
    unsigned char* Ps = lds + 24576;
    const int tid = threadIdx.x, lane = tid & 63, w = tid >> 6;

    for (int c = tid; c < 512; c += 256) {
        int row = c >> 3, cc = c & 7;
        const unsigned short* src = Y + (size_t)(b * 64 + row) * NQKV + h * 64 + cc * 8;
        *reinterpret_cast<int4*>(Qs + row * 128 + ((cc ^ (row & 7)) << 4)) =
            *reinterpret_cast<const int4*>(src);
        *reinterpret_cast<int4*>(Ks + row * 128 + ((cc ^ (row & 7)) << 4)) =
            *reinterpret_cast<const int4*>(src + 768);
        int4 vv = *reinterpret_cast<const int4*>(src + 1536);
        const unsigned short* vs = reinterpret_cast<const unsigned short*>(&vv);
#pragma unroll
        for (int u = 0; u < 8; ++u) {
            int d = cc * 8 + u;
            *reinterpret_cast<unsigned short*>(
                Vt + d * 128 + (((row >> 3) ^ u) << 4) + ((row & 7) << 1)) = vs[u];
        }
    }
    __syncthreads();

    f32x4 accS[4] = {};
#pragma unroll
    for (int kk = 0; kk < 2; ++kk) {
        const int g = kk * 4 + (lane >> 4);
        int qrow = w * 16 + (lane & 15);
        bf16x8 a = *reinterpret_cast<const bf16x8*>(Qs + qrow * 128 + ((g ^ (qrow & 7)) << 4));
#pragma unroll
        for (int j = 0; j < 4; ++j) {
            int krow = j * 16 + (lane & 15);
            bf16x8 bb = *reinterpret_cast<const bf16x8*>(Ks + krow * 128 + ((g ^ (krow & 7)) << 4));
            accS[j] = __builtin_amdgcn_mfma_f32_16x16x32_bf16(a, bb, accS[j], 0, 0, 0);
        }
    }

#pragma unroll
    for (int r = 0; r < 4; ++r) {
        float v0 = accS[0][r], v1 = accS[1][r], v2 = accS[2][r], v3 = accS[3][r];
        float mx = fmaxf(fmaxf(v0, v1), fmaxf(v2, v3));
        mx = fmaxf(mx, __shfl_xor(mx, 1));
        mx = fmaxf(mx, __shfl_xor(mx, 2));
        mx = fmaxf(mx, __shfl_xor(mx, 4));
        mx = fmaxf(mx, __shfl_xor(mx, 8));
        float p0 = __expf((v0 - mx) * 0.125f);
        float p1 = __expf((v1 - mx) * 0.125f);
        float p2 = __expf((v2 - mx) * 0.125f);
        float p3 = __expf((v3 - mx) * 0.125f);
        float sm = p0 + p1 + p2 + p3;
        sm += __shfl_xor(sm, 1);
        sm += __shfl_xor(sm, 2);
        sm += __shfl_xor(sm, 4);
        sm += __shfl_xor(sm, 8);
        float inv = 1.0f / sm;
        int srow = w * 16 + ((lane >> 4) << 2) + r;
        float pv[4] = {p0 * inv, p1 * inv, p2 * inv, p3 * inv};
#pragma unroll
        for (int j = 0; j < 4; ++j) {
            int t = j * 16 + (lane & 15);
            *reinterpret_cast<unsigned short*>(
                Ps + srow * 128 + (((t >> 3) ^ (srow & 7)) << 4) + ((t & 7) << 1)) = f2bf(pv[j]);
        }
    }
    __syncthreads();

    f32x4 accO[4] = {};
#pragma unroll
    for (int kk = 0; kk < 2; ++kk) {
        const int g = kk * 4 + (lane >> 4);
        int prow = w * 16 + (lane & 15);
        bf16x8 a = *reinterpret_cast<const bf16x8*>(Ps + prow * 128 + ((g ^ (prow & 7)) << 4));
#pragma unroll
        for (int j = 0; j < 4; ++j) {
            int drow = j * 16 + (lane & 15);
            bf16x8 bb = *reinterpret_cast<const bf16x8*>(Vt + drow * 128 + ((g ^ (drow & 7)) << 4));
            accO[j] = __builtin_amdgcn_mfma_f32_16x16x32_bf16(a, bb, accO[j], 0, 0, 0);
        }
    }

#pragma unroll
    for (int j = 0; j < 4; ++j) {
        int d = h * 64 + j * 16 + (lane & 15);
#pragma unroll
        for (int r = 0; r < 4; ++r) {
            int s = w * 16 + ((lane >> 4) << 2) + r;
            O[(size_t)(b * 64 + s) * 768 + d] = f2bf(accO[j][r]);
        }
    }
}

// ---------------------------------------------------------------------------
extern "C" void kernel_launch(void* const* d_in, const int* in_sizes, int n_in,
                              void* d_out, int out_size, void* d_ws, size_t ws_size,
                              hipStream_t stream) {
    const float* x  = (const float*)d_in[0];
    const float* Wq = (const float*)d_in[1];
    const float* bq = (const float*)d_in[2];
    const float* Wk = (const float*)d_in[3];
    const float* bk = (const float*)d_in[4];
    const float* Wv = (const float*)d_in[5];
    const float* bv = (const float*)d_in[6];
    const float* Wo = (const float*)d_in[7];
    const float* bo = (const float*)d_in[8];
    float* out = (float*)d_out;
    char* ws = (char*)d_ws;

    unsigned short* xw   = (unsigned short*)(ws);              //  6,291,456 B
    unsigned short* Wqkv = (unsigned short*)(ws + 6291456);    //  3,538,944 B
    unsigned short* Wob  = (unsigned short*)(ws + 9830400);    //  1,179,648 B
    float*          bqv  = (float*)(ws + 11010048);            //      9,216 B
    unsigned short* Y    = (unsigned short*)(ws + 11019264);   // 18,874,368 B
    unsigned short* Obuf = (unsigned short*)(ws + 29893632);   //  6,291,456 B

    prep_kernel<<<5379, 256, 0, stream>>>(x, Wq, Wk, Wv, Wo, bq, bk, bv,
                                          xw, Wqkv, Wob, bqv);
    mega_kernel<<<2624, 256, 0, stream>>>(x, out, xw, Wqkv, bqv, Y);
    attn_kernel<<<768, 256, 0, stream>>>(Y, Obuf);
    oproj_kernel<<<dim3(12, 64), 256, 0, stream>>>(Obuf, Wob, bo, out);
}

// Round 4
// 400.673 us; speedup vs baseline: 1.0345x; 1.0332x over previous
//
#include <hip/hip_runtime.h>

#define B_   64
#define S_   1024
#define F_   768
#define H_   12
#define DH_  64
#define P2_  64
#define NQKV 2304   // 3*768

using bf16x8 = __attribute__((ext_vector_type(8))) short;
using f32x4  = __attribute__((ext_vector_type(4))) float;

__device__ __forceinline__ unsigned short f2bf(float f) {
    union { float f; unsigned u; } v;
    v.f = f;
    unsigned r = v.u + 0x7FFF + ((v.u >> 16) & 1);   // RNE
    return (unsigned short)(r >> 16);
}

// async global->LDS, 16B per lane. LDS dst must be wave-uniform base;
// HW writes dst + lane*16. Global src is per-lane.
__device__ __forceinline__ void gll16(const unsigned short* g, unsigned char* l) {
    __builtin_amdgcn_global_load_lds(
        (const __attribute__((address_space(1))) unsigned int*)g,
        (__attribute__((address_space(3))) unsigned int*)l, 16, 0, 0);
}

// tail-copy role: copy cnt4 float4s of x[:,64:,:] -> out[:,64:,:] starting at
// tail-flat-index off4. 184320 = 960*768/4 tail float4s per batch.
__device__ __forceinline__ void copy_role(const float* __restrict__ x,
                                          float* __restrict__ out,
                                          int off4, int cnt4, int nblk, int bid) {
    int stride = nblk * 256;
    for (int i = bid * 256 + threadIdx.x; i < cnt4; i += stride) {
        int j = off4 + i;
        int b = j / 184320, r = j - b * 184320;
        int idx = b * 196608 + 12288 + r;
        reinterpret_cast<float4*>(out)[idx] =
            reinterpret_cast<const float4*>(x)[idx];
    }
}

// ---------------------------------------------------------------------------
// prep: cast x-window -> xw bf16, Wq|Wk|Wv -> Wqkv bf16, Wo -> Wob bf16,
//       concat bq|bk|bv -> bqv f32.
// ---------------------------------------------------------------------------
__global__ __launch_bounds__(256) void prep_kernel(
        const float* __restrict__ x,
        const float* __restrict__ Wq, const float* __restrict__ Wk,
        const float* __restrict__ Wv, const float* __restrict__ Wo,
        const float* __restrict__ bq, const float* __restrict__ bk,
        const float* __restrict__ bv,
        unsigned short* __restrict__ xw, unsigned short* __restrict__ Wqkv,
        unsigned short* __restrict__ Wob, float* __restrict__ bqv) {
    const int NW = 786432;            // 64 * 64*768/4  (window float4s)
    const int W4 = 147456;            // 768*768/4
    int i = blockIdx.x * 256 + threadIdx.x;
    if (i < NW) {
        int b = i / 12288, r = i - b * 12288;          // 12288 = 64*768/4
        float4 v = reinterpret_cast<const float4*>(x)[b * 196608 + r];
        ushort4 h;
        h.x = f2bf(v.x); h.y = f2bf(v.y); h.z = f2bf(v.z); h.w = f2bf(v.w);
        reinterpret_cast<ushort4*>(xw)[i] = h;
    } else if (i < NW + 3 * W4) {
        int j = i - NW;
        int which = j / W4, local = j - which * W4;
        const float* src = (which == 0) ? Wq : (which == 1) ? Wk : Wv;
        float4 v = reinterpret_cast<const float4*>(src)[local];
        ushort4 h;
        h.x = f2bf(v.x); h.y = f2bf(v.y); h.z = f2bf(v.z); h.w = f2bf(v.w);
        reinterpret_cast<ushort4*>(Wqkv)[j] = h;
    } else if (i < NW + 4 * W4) {
        int local = i - NW - 3 * W4;
        float4 v = reinterpret_cast<const float4*>(Wo)[local];
        ushort4 h;
        h.x = f2bf(v.x); h.y = f2bf(v.y); h.z = f2bf(v.z); h.w = f2bf(v.w);
        reinterpret_cast<ushort4*>(Wob)[local] = h;
    } else if (i < NW + 4 * W4 + 576) {
        int j4 = i - NW - 4 * W4;                       // 0..575
        int seg = j4 / 192, local = j4 - seg * 192;
        const float* src = (seg == 0) ? bq : (seg == 1) ? bk : bv;
        reinterpret_cast<float4*>(bqv)[j4] =
            reinterpret_cast<const float4*>(src)[local];
    }
}

// ---------------------------------------------------------------------------
// GEMM body: C[M,N] = A[M,768] * B[N,768]^T + bias[N]
//   bf16 row-major operands. BK=64, 4 waves. global_load_lds 16B staging:
//   linear LDS dest, inverse-XOR-swizzled global source; XOR-swizzled read
//   (chunk ^= row&7) so ds_read_b128 is conflict-free.
// ---------------------------------------------------------------------------
template <int BM, int BN, int OUT_MODE>
__device__ __forceinline__ void gemm_body(
        int bx, int by,
        const unsigned short* __restrict__ A, const unsigned short* __restrict__ Bw,
        const float* __restrict__ bias, void* __restrict__ Cout) {
    constexpr int WC = (BN == 128) ? 2 : 1;
    constexpr int WR = 4 / WC;
    constexpr int MI = BM / WR / 16;
    constexpr int NJ = BN / WC / 16;
    constexpr int CA = BM / 32;       // gll16 calls/wave for A-tile
    constexpr int CB = BN / 32;
    __shared__ __align__(16) unsigned char lds[(BM + BN) * 128];
    unsigned char* As = lds;
    unsigned char* Bs = lds + BM * 128;
    const int tid  = threadIdx.x;
    const int lane = tid & 63;
    const int w    = tid >> 6;
    const int wr = w / WC, wc = w % WC;
    const int mbase = wr * (BM / WR), nbase = wc * (BN / WC);
    const int m0 = by * BM, n0 = bx * BN;
    const int lr = lane >> 3, lc = lane & 7;   // staging sub-coords

    f32x4 acc[MI][NJ] = {};

    for (int kt = 0; kt < 768; kt += 64) {
        __syncthreads();
#pragma unroll
        for (int p = 0; p < CA; ++p) {
            int row = (w * CA + p) * 8 + lr;
            gll16(A + (size_t)(m0 + row) * 768 + kt + ((lc ^ (row & 7)) << 3),
                  As + (w * CA + p) * 1024);
        }
#pragma unroll
        for (int p = 0; p < CB; ++p) {
            int row = (w * CB + p) * 8 + lr;
            gll16(Bw + (size_t)(n0 + row) * 768 + kt + ((lc ^ (row & 7)) << 3),
                  Bs + (w * CB + p) * 1024);
        }
        __syncthreads();
#pragma unroll
        for (int kk = 0; kk < 2; ++kk) {
            const int g = kk * 4 + (lane >> 4);
            bf16x8 a[MI], b[NJ];
#pragma unroll
            for (int i = 0; i < MI; ++i) {
                int row = mbase + i * 16 + (lane & 15);
                a[i] = *reinterpret_cast<const bf16x8*>(As + row * 128 + ((g ^ (row & 7)) << 4));
            }
#pragma unroll
            for (int j = 0; j < NJ; ++j) {
                int row = nbase + j * 16 + (lane & 15);
                b[j] = *reinterpret_cast<const bf16x8*>(Bs + row * 128 + ((g ^ (row & 7)) << 4));
            }
#pragma unroll
            for (int i = 0; i < MI; ++i)
#pragma unroll
                for (int j = 0; j < NJ; ++j)
                    acc[i][j] = __builtin_amdgcn_mfma_f32_16x16x32_bf16(a[i], b[j], acc[i][j], 0, 0, 0);
        }
    }

    float bj[NJ];
#pragma unroll
    for (int j = 0; j < NJ; ++j) bj[j] = bias[n0 + nbase + j * 16 + (lane & 15)];

#pragma unroll
    for (int i = 0; i < MI; ++i) {
        int mrow = m0 + mbase + i * 16 + ((lane >> 4) << 2);
#pragma unroll
        for (int j = 0; j < NJ; ++j) {
            int n = n0 + nbase + j * 16 + (lane & 15);
#pragma unroll
            for (int r = 0; r < 4; ++r) {
                float v = acc[i][j][r] + bj[j];
                if constexpr (OUT_MODE == 0) {
                    reinterpret_cast<unsigned short*>(Cout)[(size_t)(mrow + r) * 2304 + n] = f2bf(v);
                } else {
                    int m = mrow + r;
                    reinterpret_cast<float*>(Cout)[(size_t)(m >> 6) * 786432 + (m & 63) * 768 + n] = v;
                }
            }
        }
    }
}

// ---------------------------------------------------------------------------
// mega: blocks [0,576) run the QKV GEMM (critical path, starts immediately);
// blocks [576, 2112) stream 60% of the tail copy into the freed CU slots.
// ---------------------------------------------------------------------------
__global__ __launch_bounds__(256) void mega_kernel(
        const float* __restrict__ x, float* __restrict__ out,
        const unsigned short* __restrict__ xw, const unsigned short* __restrict__ Wqkv,
        const float* __restrict__ bqv, unsigned short* __restrict__ Y) {
    if (blockIdx.x < 576) {
        gemm_body<128, 128, 0>(blockIdx.x % 18, blockIdx.x / 18, xw, Wqkv, bqv, (void*)Y);
    } else {
        copy_role(x, out, 0, 7077888, 1536, blockIdx.x - 576);
    }
}

// oproj: blocks [0,768) do the 64x64-tile output projection; [768,1792)
// stream 30% of the tail copy.
__global__ __launch_bounds__(256) void oproj_kernel(
        const unsigned short* __restrict__ Obuf, const unsigned short* __restrict__ Wob,
        const float* __restrict__ bo, float* __restrict__ out,
        const float* __restrict__ x) {
    if (blockIdx.x < 768) {
        gemm_body<64, 64, 1>(blockIdx.x % 12, blockIdx.x / 12, Obuf, Wob, bo, (void*)out);
    } else {
        copy_role(x, out, 8257536, 3538944, 1024, blockIdx.x - 768);
    }
}

// ---------------------------------------------------------------------------
// Attention: blocks [0,768) = one (b,h) each; blocks [768,1280) stream 10%
// of the tail copy. Q,K row-major swizzled in LDS; V transposed.
// ---------------------------------------------------------------------------
__global__ __launch_bounds__(256) void attn_kernel(
        const unsigned short* __restrict__ Y, unsigned short* __restrict__ O,
        const float* __restrict__ x, float* __restrict__ out) {
    if (blockIdx.x >= 768) {
        copy_role(x, out, 7077888, 1179648, 512, blockIdx.x - 768);
        return;
    }
    const int bh = blockIdx.x;
    const int b = bh / 12, h = bh % 12;
    __shared__ __align__(16) unsigned char lds[32768];
    unsigned char* Qs = lds;
    unsigned char* Ks = lds + 8192;
    unsigned char* Vt = lds + 16384;
    unsigned char* Ps = lds + 24576;
    const int tid = threadIdx.x, lane = tid & 63, w = tid >> 6;

    for (int c = tid; c < 512; c += 256) {
        int row = c >> 3, cc = c & 7;
        const unsigned short* src = Y + (size_t)(b * 64 + row) * NQKV + h * 64 + cc * 8;
        *reinterpret_cast<int4*>(Qs + row * 128 + ((cc ^ (row & 7)) << 4)) =
            *reinterpret_cast<const int4*>(src);
        *reinterpret_cast<int4*>(Ks + row * 128 + ((cc ^ (row & 7)) << 4)) =
            *reinterpret_cast<const int4*>(src + 768);
        int4 vv = *reinterpret_cast<const int4*>(src + 1536);
        const unsigned short* vs = reinterpret_cast<const unsigned short*>(&vv);
#pragma unroll
        for (int u = 0; u < 8; ++u) {
            int d = cc * 8 + u;
            *reinterpret_cast<unsigned short*>(
                Vt + d * 128 + (((row >> 3) ^ u) << 4) + ((row & 7) << 1)) = vs[u];
        }
    }
    __syncthreads();

    f32x4 accS[4] = {};
#pragma unroll
    for (int kk = 0; kk < 2; ++kk) {
        const int g = kk * 4 + (lane >> 4);
        int qrow = w * 16 + (lane & 15);
        bf16x8 a = *reinterpret_cast<const bf16x8*>(Qs + qrow * 128 + ((g ^ (qrow & 7)) << 4));
#pragma unroll
        for (int j = 0; j < 4; ++j) {
            int krow = j * 16 + (lane & 15);
            bf16x8 bb = *reinterpret_cast<const bf16x8*>(Ks + krow * 128 + ((g ^ (krow & 7)) << 4));
            accS[j] = __builtin_amdgcn_mfma_f32_16x16x32_bf16(a, bb, accS[j], 0, 0, 0);
        }
    }

#pragma unroll
    for (int r = 0; r < 4; ++r) {
        float v0 = accS[0][r], v1 = accS[1][r], v2 = accS[2][r], v3 = accS[3][r];
        float mx = fmaxf(fmaxf(v0, v1), fmaxf(v2, v3));
        mx = fmaxf(mx, __shfl_xor(mx, 1));
        mx = fmaxf(mx, __shfl_xor(mx, 2));
        mx = fmaxf(mx, __shfl_xor(mx, 4));
        mx = fmaxf(mx, __shfl_xor(mx, 8));
        float p0 = __expf((v0 - mx) * 0.125f);
        float p1 = __expf((v1 - mx) * 0.125f);
        float p2 = __expf((v2 - mx) * 0.125f);
        float p3 = __expf((v3 - mx) * 0.125f);
        float sm = p0 + p1 + p2 + p3;
        sm += __shfl_xor(sm, 1);
        sm += __shfl_xor(sm, 2);
        sm += __shfl_xor(sm, 4);
        sm += __shfl_xor(sm, 8);
        float inv = 1.0f / sm;
        int srow = w * 16 + ((lane >> 4) << 2) + r;
        float pv[4] = {p0 * inv, p1 * inv, p2 * inv, p3 * inv};
#pragma unroll
        for (int j = 0; j < 4; ++j) {
            int t = j * 16 + (lane & 15);
            *reinterpret_cast<unsigned short*>(
                Ps + srow * 128 + (((t >> 3) ^ (srow & 7)) << 4) + ((t & 7) << 1)) = f2bf(pv[j]);
        }
    }
    __syncthreads();

    f32x4 accO[4] = {};
#pragma unroll
    for (int kk = 0; kk < 2; ++kk) {
        const int g = kk * 4 + (lane >> 4);
        int prow = w * 16 + (lane & 15);
        bf16x8 a = *reinterpret_cast<const bf16x8*>(Ps + prow * 128 + ((g ^ (prow & 7)) << 4));
#pragma unroll
        for (int j = 0; j < 4; ++j) {
            int drow = j * 16 + (lane & 15);
            bf16x8 bb = *reinterpret_cast<const bf16x8*>(Vt + drow * 128 + ((g ^ (drow & 7)) << 4));
            accO[j] = __builtin_amdgcn_mfma_f32_16x16x32_bf16(a, bb, accO[j], 0, 0, 0);
        }
    }

#pragma unroll
    for (int j = 0; j < 4; ++j) {
        int d = h * 64 + j * 16 + (lane & 15);
#pragma unroll
        for (int r = 0; r < 4; ++r) {
            int s = w * 16 + ((lane >> 4) << 2) + r;
            O[(size_t)(b * 64 + s) * 768 + d] = f2bf(accO[j][r]);
        }
    }
}

// ---------------------------------------------------------------------------
extern "C" void kernel_launch(void* const* d_in, const int* in_sizes, int n_in,
                              void* d_out, int out_size, void* d_ws, size_t ws_size,
                              hipStream_t stream) {
    const float* x  = (const float*)d_in[0];
    const float* Wq = (const float*)d_in[1];
    const float* bq = (const float*)d_in[2];
    const float* Wk = (const float*)d_in[3];
    const float* bk = (const float*)d_in[4];
    const float* Wv = (const float*)d_in[5];
    const float* bv = (const float*)d_in[6];
    const float* Wo = (const float*)d_in[7];
    const float* bo = (const float*)d_in[8];
    float* out = (float*)d_out;
    char* ws = (char*)d_ws;

    unsigned short* xw   = (unsigned short*)(ws);              //  6,291,456 B
    unsigned short* Wqkv = (unsigned short*)(ws + 6291456);    //  3,538,944 B
    unsigned short* Wob  = (unsigned short*)(ws + 9830400);    //  1,179,648 B
    float*          bqv  = (float*)(ws + 11010048);            //      9,216 B
    unsigned short* Y    = (unsigned short*)(ws + 11019264);   // 18,874,368 B
    unsigned short* Obuf = (unsigned short*)(ws + 29893632);   //  6,291,456 B

    prep_kernel<<<5379, 256, 0, stream>>>(x, Wq, Wk, Wv, Wo, bq, bk, bv,
                                          xw, Wqkv, Wob, bqv);
    mega_kernel<<<2112, 256, 0, stream>>>(x, out, xw, Wqkv, bqv, Y);
    attn_kernel<<<1280, 256, 0, stream>>>(Y, Obuf, x, out);
    oproj_kernel<<<1792, 256, 0, stream>>>(Obuf, Wob, bo, out, x);
}

// Round 5
// 388.653 us; speedup vs baseline: 1.0665x; 1.0309x over previous
//
#include <hip/hip_runtime.h>

#define B_   64
#define S_   1024
#define F_   768
#define H_   12
#define DH_  64
#define P2_  64

using bf16x8 = __attribute__((ext_vector_type(8))) short;
using f32x4  = __attribute__((ext_vector_type(4))) float;

__device__ __forceinline__ unsigned short f2bf(float f) {
    union { float f; unsigned u; } v;
    v.f = f;
    unsigned r = v.u + 0x7FFF + ((v.u >> 16) & 1);   // RNE
    return (unsigned short)(r >> 16);
}

// async global->LDS, 16B per lane. LDS dst is wave-uniform base + lane*16.
__device__ __forceinline__ void gll16(const unsigned short* g, unsigned char* l) {
    __builtin_amdgcn_global_load_lds(
        (const __attribute__((address_space(1))) unsigned int*)g,
        (__attribute__((address_space(3))) unsigned int*)l, 16, 0, 0);
}

// tail-copy role: copy cnt4 float4s of x[:,64:,:] -> out[:,64:,:] starting at
// tail-flat-index off4. 184320 = 960*768/4 tail float4s per batch.
__device__ __forceinline__ void copy_role(const float* __restrict__ x,
                                          float* __restrict__ out,
                                          int off4, int cnt4, int nblk, int bid) {
    int stride = nblk * 256;
    for (int i = bid * 256 + threadIdx.x; i < cnt4; i += stride) {
        int j = off4 + i;
        int b = j / 184320, r = j - b * 184320;
        int idx = b * 196608 + 12288 + r;
        reinterpret_cast<float4*>(out)[idx] =
            reinterpret_cast<const float4*>(x)[idx];
    }
}

// ---------------------------------------------------------------------------
// prep: cast x-window -> xw bf16, Wq|Wk|Wv -> Wqkv bf16, Wo -> Wob bf16,
//       concat bq|bk|bv -> bqv f32. Blocks >= 5379 stream 20% of tail copy.
// ---------------------------------------------------------------------------
__global__ __launch_bounds__(256) void prep_kernel(
        const float* __restrict__ x,
        const float* __restrict__ Wq, const float* __restrict__ Wk,
        const float* __restrict__ Wv, const float* __restrict__ Wo,
        const float* __restrict__ bq, const float* __restrict__ bk,
        const float* __restrict__ bv,
        unsigned short* __restrict__ xw, unsigned short* __restrict__ Wqkv,
        unsigned short* __restrict__ Wob, float* __restrict__ bqv,
        float* __restrict__ out) {
    const int NW = 786432;            // 64 * 64*768/4  (window float4s)
    const int W4 = 147456;            // 768*768/4
    if (blockIdx.x >= 5379) {
        copy_role(x, out, 0, 2359296, 1024, blockIdx.x - 5379);
        return;
    }
    int i = blockIdx.x * 256 + threadIdx.x;
    if (i < NW) {
        int b = i / 12288, r = i - b * 12288;          // 12288 = 64*768/4
        float4 v = reinterpret_cast<const float4*>(x)[b * 196608 + r];
        ushort4 h;
        h.x = f2bf(v.x); h.y = f2bf(v.y); h.z = f2bf(v.z); h.w = f2bf(v.w);
        reinterpret_cast<ushort4*>(xw)[i] = h;
    } else if (i < NW + 3 * W4) {
        int j = i - NW;
        int which = j / W4, local = j - which * W4;
        const float* src = (which == 0) ? Wq : (which == 1) ? Wk : Wv;
        float4 v = reinterpret_cast<const float4*>(src)[local];
        ushort4 h;
        h.x = f2bf(v.x); h.y = f2bf(v.y); h.z = f2bf(v.z); h.w = f2bf(v.w);
        reinterpret_cast<ushort4*>(Wqkv)[j] = h;
    } else if (i < NW + 4 * W4) {
        int local = i - NW - 3 * W4;
        float4 v = reinterpret_cast<const float4*>(Wo)[local];
        ushort4 h;
        h.x = f2bf(v.x); h.y = f2bf(v.y); h.z = f2bf(v.z); h.w = f2bf(v.w);
        reinterpret_cast<ushort4*>(Wob)[local] = h;
    } else if (i < NW + 4 * W4 + 576) {
        int j4 = i - NW - 4 * W4;                       // 0..575
        int seg = j4 / 192, local = j4 - seg * 192;
        const float* src = (seg == 0) ? bq : (seg == 1) ? bk : bv;
        reinterpret_cast<float4*>(bqv)[j4] =
            reinterpret_cast<const float4*>(src)[local];
    }
}

// ---------------------------------------------------------------------------
// Fused QKV projection + attention. One compute block per (b,h).
//   Phase 1: C[64 s][192 c] = xw[b] (64x768) @ Wqkv[h-slice]^T (+bias later).
//            4 waves, wave w owns rows w*16..w*16+16, all 192 cols (NJ=12).
//   Phase 2: epilogue writes Q,K (row-major swizzled) and V (transposed
//            swizzled) straight into the attention LDS buffers.
//   Phase 3: QK^T/8 -> in-register softmax -> PV -> write Obuf (bf16).
// Blocks >= 768 stream 40% of the tail copy.
// ---------------------------------------------------------------------------
__global__ __launch_bounds__(256) void fused_kernel(
        const unsigned short* __restrict__ xw, const unsigned short* __restrict__ Wqkv,
        const float* __restrict__ bqv, unsigned short* __restrict__ O,
        const float* __restrict__ x, float* __restrict__ out) {
    if (blockIdx.x >= 768) {
        copy_role(x, out, 2359296, 4718592, 1280, blockIdx.x - 768);
        return;
    }
    const int b = blockIdx.x / 12, h = blockIdx.x % 12;
    __shared__ __align__(16) unsigned char lds[32768];
    unsigned char* As = lds;            //  8 KB: xw tile 64 rows x 64 k
    unsigned char* Bs = lds + 8192;     // 24 KB: Wqkv tile 192 rows x 64 k
    unsigned char* Qs = lds;            // attn phase aliases (after barrier)
    unsigned char* Ks = lds + 8192;
    unsigned char* Vt = lds + 16384;
    unsigned char* Ps = lds + 24576;
    const int tid = threadIdx.x, lane = tid & 63, w = tid >> 6;
    const int lr = lane >> 3, lc = lane & 7;

    // ---- Phase 1: projection GEMM ----
    f32x4 acc[12] = {};
    for (int kt = 0; kt < 768; kt += 64) {
        __syncthreads();
#pragma unroll
        for (int p = 0; p < 2; ++p) {            // A: 8 KB
            int row = (w * 2 + p) * 8 + lr;      // 0..63
            gll16(xw + (size_t)(b * 64 + row) * 768 + kt + ((lc ^ (row & 7)) << 3),
                  As + (w * 2 + p) * 1024);
        }
#pragma unroll
        for (int p = 0; p < 6; ++p) {            // B: 24 KB
            int idx = w * 6 + p;                 // 0..23
            int row = idx * 8 + lr;              // 0..191
            int seg = row >> 6, rr = row & 63;
            gll16(Wqkv + (size_t)(seg * 768 + h * 64 + rr) * 768 + kt + ((lc ^ (row & 7)) << 3),
                  Bs + idx * 1024);
        }
        __syncthreads();
#pragma unroll
        for (int kk = 0; kk < 2; ++kk) {
            const int g = kk * 4 + (lane >> 4);
            int arow = w * 16 + (lane & 15);
            bf16x8 a = *reinterpret_cast<const bf16x8*>(As + arow * 128 + ((g ^ (arow & 7)) << 4));
#pragma unroll
            for (int j = 0; j < 12; ++j) {
                int brow = j * 16 + (lane & 15);
                bf16x8 bb = *reinterpret_cast<const bf16x8*>(Bs + brow * 128 + ((g ^ (brow & 7)) << 4));
                acc[j] = __builtin_amdgcn_mfma_f32_16x16x32_bf16(a, bb, acc[j], 0, 0, 0);
            }
        }
    }

    // ---- Phase 2: bias + cast + scatter into attention LDS layouts ----
    __syncthreads();                    // all waves done reading As/Bs
#pragma unroll
    for (int j = 0; j < 12; ++j) {
        int seg = j >> 2;                         // 0=Q 1=K 2=V
        int d = (j & 3) * 16 + (lane & 15);       // 0..63
        float bb = bqv[seg * 768 + h * 64 + d];
#pragma unroll
        for (int r = 0; r < 4; ++r) {
            int srow = w * 16 + ((lane >> 4) << 2) + r;
            unsigned short hv = f2bf(acc[j][r] + bb);
            if (seg == 0) {
                *reinterpret_cast<unsigned short*>(Qs + srow * 128 +
                    (((d >> 3) ^ (srow & 7)) << 4) + ((d & 7) << 1)) = hv;
            } else if (seg == 1) {
                *reinterpret_cast<unsigned short*>(Ks + srow * 128 +
                    (((d >> 3) ^ (srow & 7)) << 4) + ((d & 7) << 1)) = hv;
            } else {
                *reinterpret_cast<unsigned short*>(Vt + d * 128 +
                    (((srow >> 3) ^ (d & 7)) << 4) + ((srow & 7) << 1)) = hv;
            }
        }
    }
    __syncthreads();

    // ---- Phase 3: attention ----
    f32x4 accS[4] = {};
#pragma unroll
    for (int kk = 0; kk < 2; ++kk) {
        const int g = kk * 4 + (lane >> 4);
        int qrow = w * 16 + (lane & 15);
        bf16x8 a = *reinterpret_cast<const bf16x8*>(Qs + qrow * 128 + ((g ^ (qrow & 7)) << 4));
#pragma unroll
        for (int j = 0; j < 4; ++j) {
            int krow = j * 16 + (lane & 15);
            bf16x8 bb = *reinterpret_cast<const bf16x8*>(Ks + krow * 128 + ((g ^ (krow & 7)) << 4));
            accS[j] = __builtin_amdgcn_mfma_f32_16x16x32_bf16(a, bb, accS[j], 0, 0, 0);
        }
    }

#pragma unroll
    for (int r = 0; r < 4; ++r) {
        float v0 = accS[0][r], v1 = accS[1][r], v2 = accS[2][r], v3 = accS[3][r];
        float mx = fmaxf(fmaxf(v0, v1), fmaxf(v2, v3));
        mx = fmaxf(mx, __shfl_xor(mx, 1));
        mx = fmaxf(mx, __shfl_xor(mx, 2));
        mx = fmaxf(mx, __shfl_xor(mx, 4));
        mx = fmaxf(mx, __shfl_xor(mx, 8));
        float p0 = __expf((v0 - mx) * 0.125f);
        float p1 = __expf((v1 - mx) * 0.125f);
        float p2 = __expf((v2 - mx) * 0.125f);
        float p3 = __expf((v3 - mx) * 0.125f);
        float sm = p0 + p1 + p2 + p3;
        sm += __shfl_xor(sm, 1);
        sm += __shfl_xor(sm, 2);
        sm += __shfl_xor(sm, 4);
        sm += __shfl_xor(sm, 8);
        float inv = 1.0f / sm;
        int srow = w * 16 + ((lane >> 4) << 2) + r;
        float pv[4] = {p0 * inv, p1 * inv, p2 * inv, p3 * inv};
#pragma unroll
        for (int j = 0; j < 4; ++j) {
            int t = j * 16 + (lane & 15);
            *reinterpret_cast<unsigned short*>(
                Ps + srow * 128 + (((t >> 3) ^ (srow & 7)) << 4) + ((t & 7) << 1)) = f2bf(pv[j]);
        }
    }
    __syncthreads();

    f32x4 accO[4] = {};
#pragma unroll
    for (int kk = 0; kk < 2; ++kk) {
        const int g = kk * 4 + (lane >> 4);
        int prow = w * 16 + (lane & 15);
        bf16x8 a = *reinterpret_cast<const bf16x8*>(Ps + prow * 128 + ((g ^ (prow & 7)) << 4));
#pragma unroll
        for (int j = 0; j < 4; ++j) {
            int drow = j * 16 + (lane & 15);
            bf16x8 bb = *reinterpret_cast<const bf16x8*>(Vt + drow * 128 + ((g ^ (drow & 7)) << 4));
            accO[j] = __builtin_amdgcn_mfma_f32_16x16x32_bf16(a, bb, accO[j], 0, 0, 0);
        }
    }

#pragma unroll
    for (int j = 0; j < 4; ++j) {
        int d = h * 64 + j * 16 + (lane & 15);
#pragma unroll
        for (int r = 0; r < 4; ++r) {
            int s = w * 16 + ((lane >> 4) << 2) + r;
            O[(size_t)(b * 64 + s) * 768 + d] = f2bf(accO[j][r]);
        }
    }
}

// ---------------------------------------------------------------------------
// GEMM body (oproj): C = A[M,768] * B[N,768]^T + bias, 64x64 tile, 4 waves.
// ---------------------------------------------------------------------------
template <int BM, int BN, int OUT_MODE>
__device__ __forceinline__ void gemm_body(
        int bx, int by,
        const unsigned short* __restrict__ A, const unsigned short* __restrict__ Bw,
        const float* __restrict__ bias, void* __restrict__ Cout) {
    constexpr int WC = (BN == 128) ? 2 : 1;
    constexpr int WR = 4 / WC;
    constexpr int MI = BM / WR / 16;
    constexpr int NJ = BN / WC / 16;
    constexpr int CA = BM / 32;
    constexpr int CB = BN / 32;
    __shared__ __align__(16) unsigned char lds[(BM + BN) * 128];
    unsigned char* As = lds;
    unsigned char* Bs = lds + BM * 128;
    const int tid  = threadIdx.x;
    const int lane = tid & 63;
    const int w    = tid >> 6;
    const int wr = w / WC, wc = w % WC;
    const int mbase = wr * (BM / WR), nbase = wc * (BN / WC);
    const int m0 = by * BM, n0 = bx * BN;
    const int lr = lane >> 3, lc = lane & 7;

    f32x4 acc[MI][NJ] = {};

    for (int kt = 0; kt < 768; kt += 64) {
        __syncthreads();
#pragma unroll
        for (int p = 0; p < CA; ++p) {
            int row = (w * CA + p) * 8 + lr;
            gll16(A + (size_t)(m0 + row) * 768 + kt + ((lc ^ (row & 7)) << 3),
                  As + (w * CA + p) * 1024);
        }
#pragma unroll
        for (int p = 0; p < CB; ++p) {
            int row = (w * CB + p) * 8 + lr;
            gll16(Bw + (size_t)(n0 + row) * 768 + kt + ((lc ^ (row & 7)) << 3),
                  Bs + (w * CB + p) * 1024);
        }
        __syncthreads();
#pragma unroll
        for (int kk = 0; kk < 2; ++kk) {
            const int g = kk * 4 + (lane >> 4);
            bf16x8 a[MI], b[NJ];
#pragma unroll
            for (int i = 0; i < MI; ++i) {
                int row = mbase + i * 16 + (lane & 15);
                a[i] = *reinterpret_cast<const bf16x8*>(As + row * 128 + ((g ^ (row & 7)) << 4));
            }
#pragma unroll
            for (int j = 0; j < NJ; ++j) {
                int row = nbase + j * 16 + (lane & 15);
                b[j] = *reinterpret_cast<const bf16x8*>(Bs + row * 128 + ((g ^ (row & 7)) << 4));
            }
#pragma unroll
            for (int i = 0; i < MI; ++i)
#pragma unroll
                for (int j = 0; j < NJ; ++j)
                    acc[i][j] = __builtin_amdgcn_mfma_f32_16x16x32_bf16(a[i], b[j], acc[i][j], 0, 0, 0);
        }
    }

    float bj[NJ];
#pragma unroll
    for (int j = 0; j < NJ; ++j) bj[j] = bias[n0 + nbase + j * 16 + (lane & 15)];

#pragma unroll
    for (int i = 0; i < MI; ++i) {
        int mrow = m0 + mbase + i * 16 + ((lane >> 4) << 2);
#pragma unroll
        for (int j = 0; j < NJ; ++j) {
            int n = n0 + nbase + j * 16 + (lane & 15);
#pragma unroll
            for (int r = 0; r < 4; ++r) {
                float v = acc[i][j][r] + bj[j];
                if constexpr (OUT_MODE == 0) {
                    reinterpret_cast<unsigned short*>(Cout)[(size_t)(mrow + r) * 768 + n] = f2bf(v);
                } else {
                    int m = mrow + r;
                    reinterpret_cast<float*>(Cout)[(size_t)(m >> 6) * 786432 + (m & 63) * 768 + n] = v;
                }
            }
        }
    }
}

// oproj: blocks [0,768) do the 64x64-tile output projection into the out
// window; blocks [768,2048) stream the last 40% of the tail copy.
__global__ __launch_bounds__(256) void oproj_kernel(
        const unsigned short* __restrict__ Obuf, const unsigned short* __restrict__ Wob,
        const float* __restrict__ bo, float* __restrict__ out,
        const float* __restrict__ x) {
    if (blockIdx.x < 768) {
        gemm_body<64, 64, 1>(blockIdx.x % 12, blockIdx.x / 12, Obuf, Wob, bo, (void*)out);
    } else {
        copy_role(x, out, 7077888, 4718592, 1280, blockIdx.x - 768);
    }
}

// ---------------------------------------------------------------------------
extern "C" void kernel_launch(void* const* d_in, const int* in_sizes, int n_in,
                              void* d_out, int out_size, void* d_ws, size_t ws_size,
                              hipStream_t stream) {
    const float* x  = (const float*)d_in[0];
    const float* Wq = (const float*)d_in[1];
    const float* bq = (const float*)d_in[2];
    const float* Wk = (const float*)d_in[3];
    const float* bk = (const float*)d_in[4];
    const float* Wv = (const float*)d_in[5];
    const float* bv = (const float*)d_in[6];
    const float* Wo = (const float*)d_in[7];
    const float* bo = (const float*)d_in[8];
    float* out = (float*)d_out;
    char* ws = (char*)d_ws;

    unsigned short* xw   = (unsigned short*)(ws);              //  6,291,456 B
    unsigned short* Wqkv = (unsigned short*)(ws + 6291456);    //  3,538,944 B
    unsigned short* Wob  = (unsigned short*)(ws + 9830400);    //  1,179,648 B
    float*          bqv  = (float*)(ws + 11010048);            //      9,216 B
    unsigned short* Obuf = (unsigned short*)(ws + 11019264);   //  6,291,456 B

    prep_kernel<<<6403, 256, 0, stream>>>(x, Wq, Wk, Wv, Wo, bq, bk, bv,
                                          xw, Wqkv, Wob, bqv, out);
    fused_kernel<<<2048, 256, 0, stream>>>(xw, Wqkv, bqv, Obuf, x, out);
    oproj_kernel<<<2048, 256, 0, stream>>>(Obuf, Wob, bo, out, x);
}